// Round 6
// baseline (257.548 us; speedup 1.0000x reference)
//
#include <hip/hip_runtime.h>
#include <math.h>

#define NPIX 4096
#define CCH 256

typedef __attribute__((ext_vector_type(4))) float f32x4;
typedef __attribute__((ext_vector_type(8))) short s16x8;
typedef unsigned short u16;

__device__ __forceinline__ short bf16_rne(float x) {
  union { float f; unsigned u; } c; c.f = x;
  unsigned r = c.u + 0x7FFF + ((c.u >> 16) & 1);
  return (short)(r >> 16);
}
// hardware packed f32->bf16 (RNE): lo -> bits[15:0], hi -> bits[31:16]
__device__ __forceinline__ unsigned cvtpk2(float lo, float hi) {
  unsigned r;
  asm("v_cvt_pk_bf16_f32 %0, %1, %2" : "=v"(r) : "v"(lo), "v"(hi));
  return r;
}
__device__ __forceinline__ unsigned pack2(float a, float b) {
  return cvtpk2(a, b);
}
__device__ __forceinline__ float max3f(float a, float b, float c) {
  float d;
  asm("v_max3_f32 %0, %1, %2, %3" : "=v"(d) : "v"(a), "v"(b), "v"(c));
  return d;
}
__device__ __forceinline__ float bf16_to_f32(unsigned short v) {
  return __uint_as_float(((unsigned)v) << 16);
}

// permlane swaps via builtins (compiler-managed hazards). Raw asm back-to-back
// VALU-write -> permlane-read has a wait-state hazard (R2 failure root cause).
__device__ __forceinline__ void plane32_swap(unsigned& a, unsigned& b) {
#if __has_builtin(__builtin_amdgcn_permlane32_swap)
  auto r = __builtin_amdgcn_permlane32_swap(a, b, false, false);
  a = r[0]; b = r[1];
#else
  asm("s_nop 2\n\tv_permlane32_swap_b32 %0, %1\n\ts_nop 2" : "+v"(a), "+v"(b));
#endif
}
__device__ __forceinline__ void plane16_swap(unsigned& a, unsigned& b) {
#if __has_builtin(__builtin_amdgcn_permlane16_swap)
  auto r = __builtin_amdgcn_permlane16_swap(a, b, false, false);
  a = r[0]; b = r[1];
#else
  asm("s_nop 2\n\tv_permlane16_swap_b32 %0, %1\n\ts_nop 2" : "+v"(a), "+v"(b));
#endif
}

// cross-quad reductions (over lanes {n16, n16+16, n16+32, n16+48}), VALU pipe only
__device__ __forceinline__ float red_max_cross(float x) {
  unsigned a = __float_as_uint(x), b = a;
  plane32_swap(a, b);
  float m = fmaxf(__uint_as_float(a), __uint_as_float(b));
  a = __float_as_uint(m); b = a;
  plane16_swap(a, b);
  return fmaxf(__uint_as_float(a), __uint_as_float(b));
}
__device__ __forceinline__ float red_sum_cross(float x) {
  unsigned a = __float_as_uint(x), b = a;
  plane32_swap(a, b);
  float m = __uint_as_float(a) + __uint_as_float(b);
  a = __float_as_uint(m); b = a;
  plane16_swap(a, b);
  return __uint_as_float(a) + __uint_as_float(b);
}

#define QSCALE 0.18033688011f   /* 0.125 * log2(e) */

// ---------------- GroupNorm partial stats: 256 blocks = (b, g, chunk) ----------------
__global__ __launch_bounds__(256) void gn_stats_part(
    const float* __restrict__ x, double2* __restrict__ partials)
{
  const int blk = blockIdx.x;
  const int bg = blk >> 3, chunk = blk & 7;
  const float4* base = (const float4*)(x + (size_t)bg * 131072 + (size_t)chunk * 16384);
  double s = 0.0, ss = 0.0;
  for (int idx = threadIdx.x; idx < 4096; idx += 256) {
    float4 v = base[idx];
    s  += (double)v.x + (double)v.y + (double)v.z + (double)v.w;
    ss += (double)v.x * v.x + (double)v.y * v.y + (double)v.z * v.z + (double)v.w * v.w;
  }
  __shared__ double rs[256], rss[256];
  rs[threadIdx.x] = s; rss[threadIdx.x] = ss;
  __syncthreads();
  for (int off = 128; off > 0; off >>= 1) {
    if (threadIdx.x < off) { rs[threadIdx.x] += rs[threadIdx.x + off]; rss[threadIdx.x] += rss[threadIdx.x + off]; }
    __syncthreads();
  }
  if (threadIdx.x == 0) {
    double2 p; p.x = rs[0]; p.y = rss[0];
    partials[blk] = p;
  }
}

// ---------------- Weight/bias convert + GN stats finalize ----------------
__global__ __launch_bounds__(256) void wcvt_kernel(
    const float* __restrict__ qkv_w, const float* __restrict__ proj_w, const float* __restrict__ qkv_b,
    const double2* __restrict__ partials, const float* __restrict__ gn_w, const float* __restrict__ gn_b,
    u16* __restrict__ wq, u16* __restrict__ wp, float* __restrict__ biasq,
    float* __restrict__ alpha, float* __restrict__ beta)
{
  int idx = blockIdx.x * 256 + threadIdx.x;   // 0..262143
  if (idx < 196608) {
    float v = qkv_w[idx];
    if (idx < 65536) v *= QSCALE;             // q rows (o < 256)
    wq[idx] = (u16)bf16_rne(v);
  } else {
    int j = idx - 196608;
    wp[j] = (u16)bf16_rne(proj_w[j]);
  }
  if (idx < 768) {
    float bv = qkv_b[idx];
    if (idx < 256) bv *= QSCALE;
    biasq[idx] = bv;
  }
  if (blockIdx.x == 0) {
    __shared__ float sm[32], sr[32];
    const int tid = threadIdx.x;
    if (tid < 32) {
      double s = 0.0, ss = 0.0;
      for (int c = 0; c < 8; ++c) { double2 p = partials[tid * 8 + c]; s += p.x; ss += p.y; }
      double mean = s / 131072.0;
      double var  = ss / 131072.0 - mean * mean;
      sm[tid] = (float)mean;
      sr[tid] = (float)(1.0 / sqrt(var + 1e-5));
    }
    __syncthreads();
#pragma unroll
    for (int p = 0; p < 4; ++p) {
      int e = p * 256 + tid;            // 0..1023 = b*256 + ch
      int ch = e & 255;
      int bg = (e >> 8) * 8 + (ch >> 5);
      float a = sr[bg] * gn_w[ch];
      alpha[e] = a;
      beta[e]  = gn_b[ch] - sm[bg] * a;
    }
  }
}

// ---------------- GN apply + transpose: x[b][c][n] fp32 -> Xt[b][n][c] bf16 ----------------
__global__ __launch_bounds__(256) void gn_apply_t_kernel(
    const float* __restrict__ x, const float* __restrict__ alpha, const float* __restrict__ beta,
    u16* __restrict__ Xt)
{
  const int b = blockIdx.z, c0 = blockIdx.y * 64, n0 = blockIdx.x * 64;
  const int tid = threadIdx.x;
  __shared__ u16 T[64 * 68];
  const int n4 = (tid & 15) * 4, cr = tid >> 4;
#pragma unroll
  for (int p = 0; p < 4; ++p) {
    int cl = cr + 16 * p;
    int c = c0 + cl;
    float a = alpha[b * CCH + c], bt = beta[b * CCH + c];
    float4 v = *(const float4*)&x[((size_t)b * CCH + c) * NPIX + n0 + n4];
    T[(n4 + 0) * 68 + cl] = (u16)bf16_rne(v.x * a + bt);
    T[(n4 + 1) * 68 + cl] = (u16)bf16_rne(v.y * a + bt);
    T[(n4 + 2) * 68 + cl] = (u16)bf16_rne(v.z * a + bt);
    T[(n4 + 3) * 68 + cl] = (u16)bf16_rne(v.w * a + bt);
  }
  __syncthreads();
#pragma unroll
  for (int it = 0; it < 2; ++it) {
    int linear = it * 256 + tid;
    int n = linear >> 3, ch = linear & 7;
    s16x8 v = *(const s16x8*)&T[n * 68 + ch * 8];
    *(s16x8*)&Xt[((size_t)b * NPIX + n0 + n) * CCH + c0 + ch * 8] = v;
  }
}

// ---------------- QKV GEMM (bf16 MFMA): D[m][n] = W[m][k] Xt[n][k] + bias ----------------
__global__ __launch_bounds__(256) void qkv_gemm_kernel(
    const u16* __restrict__ Wbf, const float* __restrict__ biasv, const u16* __restrict__ Xt,
    u16* __restrict__ Qt, u16* __restrict__ Kt, u16* __restrict__ Vb)
{
  const int nblk = blockIdx.x, m0 = blockIdx.y * 64;
  const int tid = threadIdx.x, wave = tid >> 6, lane = tid & 63;
  const int n16 = lane & 15, quad = lane >> 4;
  const int n0 = nblk * 128 + wave * 32;   // flat row (b*4096 + i)

  f32x4 acc[4][2];
#pragma unroll
  for (int a = 0; a < 4; ++a)
#pragma unroll
    for (int c = 0; c < 2; ++c) acc[a][c] = (f32x4){0.f, 0.f, 0.f, 0.f};

#pragma unroll
  for (int k0 = 0; k0 < 256; k0 += 32) {
    s16x8 af[4], bfr[2];
#pragma unroll
    for (int msub = 0; msub < 4; ++msub)
      af[msub] = *(const s16x8*)&Wbf[(size_t)(m0 + msub * 16 + n16) * 256 + k0 + quad * 8];
#pragma unroll
    for (int nsub = 0; nsub < 2; ++nsub)
      bfr[nsub] = *(const s16x8*)&Xt[(size_t)(n0 + nsub * 16 + n16) * 256 + k0 + quad * 8];
#pragma unroll
    for (int msub = 0; msub < 4; ++msub)
#pragma unroll
      for (int nsub = 0; nsub < 2; ++nsub)
        acc[msub][nsub] = __builtin_amdgcn_mfma_f32_16x16x32_bf16(af[msub], bfr[nsub], acc[msub][nsub], 0, 0, 0);
  }

  __shared__ u16 T[8704];   // qk: [n128][m 68]; v: [m64][n 136]
  if (m0 < 512) {
    // bias + pack, store transposed tile [n][m]
#pragma unroll
    for (int msub = 0; msub < 4; ++msub)
#pragma unroll
      for (int nsub = 0; nsub < 2; ++nsub) {
        float b0 = biasv[m0 + msub * 16 + quad * 4 + 0];
        float b1 = biasv[m0 + msub * 16 + quad * 4 + 1];
        float b2 = biasv[m0 + msub * 16 + quad * 4 + 2];
        float b3 = biasv[m0 + msub * 16 + quad * 4 + 3];
        uint2 w2;
        w2.x = pack2(acc[msub][nsub][0] + b0, acc[msub][nsub][1] + b1);
        w2.y = pack2(acc[msub][nsub][2] + b2, acc[msub][nsub][3] + b3);
        *(uint2*)&T[(wave * 32 + nsub * 16 + n16) * 68 + msub * 16 + quad * 4] = w2;
      }
    __syncthreads();
    u16* dst = (m0 < 256) ? Qt : Kt;
    const int coff = m0 & 255;
#pragma unroll
    for (int it = 0; it < 4; ++it) {
      int linear = it * 256 + tid;
      int n = linear >> 3, ch = linear & 7;
      s16x8 v = *(const s16x8*)&T[n * 68 + ch * 8];
      *(s16x8*)&dst[(size_t)(nblk * 128 + n) * 256 + coff + ch * 8] = v;
    }
  } else {
    // V: store [m][n] natural rows
#pragma unroll
    for (int msub = 0; msub < 4; ++msub)
#pragma unroll
      for (int nsub = 0; nsub < 2; ++nsub) {
        int ncol = wave * 32 + nsub * 16 + n16;
#pragma unroll
        for (int r = 0; r < 4; ++r) {
          int m = msub * 16 + quad * 4 + r;
          T[m * 136 + ncol] = (u16)bf16_rne(acc[msub][nsub][r] + biasv[m0 + m]);
        }
      }
    __syncthreads();
    const int b = (nblk * 128) >> 12, i0n = (nblk * 128) & 4095;
#pragma unroll
    for (int it = 0; it < 4; ++it) {
      int linear = it * 256 + tid;
      int mloc = linear >> 4, ch = linear & 15;
      s16x8 v = *(const s16x8*)&T[mloc * 136 + ch * 8];
      int c = (m0 - 512) + mloc;
      *(s16x8*)&Vb[((size_t)b * CCH + c) * NPIX + i0n + ch * 8] = v;
    }
  }
}

// ---------------- MFMA flash attention v5: split-KV x2 ----------------
// Grid (128,4,4): blockIdx.x>>6 = KV half, 32 tiles each. 2048 blocks -> 8/CU.
// Single-buffered K/V LDS (16.6KB) + launch_bounds(256,8) for 32 waves/CU.
// Each half writes normalized bf16 partial O + (m,l); combine_kernel merges.
__device__ __forceinline__ void kv_load(
    const u16* __restrict__ Kb, const u16* __restrict__ Vg, int h, int j0, int sj, int part,
    s16x8& k0, s16x8& k1, s16x8& v0, s16x8& v1)
{
  const s16x8* kp = (const s16x8*)&Kb[(size_t)(j0 + sj) * 256 + h * 64 + part * 16];
  const s16x8* vp = (const s16x8*)&Vg[(size_t)sj * NPIX + j0 + part * 16];
  k0 = kp[0]; k1 = kp[1]; v0 = vp[0]; v1 = vp[1];
}
__device__ __forceinline__ void kv_store(
    u16* Ksb, u16* Vsb, int sbase, int rr0,
    s16x8 k0, s16x8 k1, s16x8 v0, s16x8 v1)
{
  *(s16x8*)&Ksb[sbase + (rr0 + 0) * 128] = k0;
  *(s16x8*)&Ksb[sbase + (rr0 + 1) * 128] = k1;
  *(s16x8*)&Vsb[sbase + (rr0 + 0) * 128] = v0;
  *(s16x8*)&Vsb[sbase + (rr0 + 1) * 128] = v1;
}

__device__ __forceinline__ void attn_tile(
    const u16* Ksb, const u16* Vsb, const s16x8 qf[2], int lane,
    f32x4 ot[4], float& m_i, float& l_i)
{
  f32x4 st[4];
#pragma unroll
  for (int a = 0; a < 4; ++a) st[a] = (f32x4){0.f, 0.f, 0.f, 0.f};
  __builtin_amdgcn_s_setprio(1);
#pragma unroll
  for (int ks = 0; ks < 2; ++ks)
#pragma unroll
    for (int jsub = 0; jsub < 4; ++jsub) {
      s16x8 a = *(const s16x8*)&Ksb[(jsub * 2 + ks) * 520 + lane * 8];
      st[jsub] = __builtin_amdgcn_mfma_f32_16x16x32_bf16(a, qf[ks], st[jsub], 0, 0, 0);
    }
  __builtin_amdgcn_s_setprio(0);

  // row max: v_max3 tree (8 ops) + permlane cross-quad reduce (no LDS)
  float m0 = max3f(st[0][0], st[0][1], st[0][2]);
  float m1 = max3f(st[0][3], st[1][0], st[1][1]);
  float m2 = max3f(st[1][2], st[1][3], st[2][0]);
  float m3 = max3f(st[2][1], st[2][2], st[2][3]);
  float m4 = max3f(st[3][0], st[3][1], st[3][2]);
  float m5 = max3f(m0, m1, st[3][3]);
  float m6 = max3f(m2, m3, m4);
  float tm = fmaxf(m5, m6);
  tm = red_max_cross(tm);

  // defer-max: only rescale when max grew by >8 (log2 domain)
  if (__any(tm > m_i + 8.0f)) {
    float mn = fmaxf(m_i, tm);
    float al = __builtin_amdgcn_exp2f(m_i - mn);
    m_i = mn;
    l_i *= al;
#pragma unroll
    for (int dsub = 0; dsub < 4; ++dsub)
#pragma unroll
      for (int r = 0; r < 4; ++r) ot[dsub][r] *= al;
  }

#pragma unroll
  for (int jsub = 0; jsub < 4; ++jsub)
#pragma unroll
    for (int r = 0; r < 4; ++r)
      st[jsub][r] = __builtin_amdgcn_exp2f(st[jsub][r] - m_i);

  float s0 = (st[0][0] + st[0][1]) + (st[0][2] + st[0][3]);
  float s1 = (st[1][0] + st[1][1]) + (st[1][2] + st[1][3]);
  float s2 = (st[2][0] + st[2][1]) + (st[2][2] + st[2][3]);
  float s3 = (st[3][0] + st[3][1]) + (st[3][2] + st[3][3]);
  float ps = (s0 + s1) + (s2 + s3);
  ps = red_sum_cross(ps);
  l_i += ps;

  // P (C-frag, rows j) -> PV B-frags: pack pairs then permlane32+16 swap.
  s16x8 pb[2];
#pragma unroll
  for (int ks = 0; ks < 2; ++ks) {
    unsigned a0 = cvtpk2(st[2 * ks][0], st[2 * ks][1]);
    unsigned a1 = cvtpk2(st[2 * ks][2], st[2 * ks][3]);
    unsigned b0 = cvtpk2(st[2 * ks + 1][0], st[2 * ks + 1][1]);
    unsigned b1 = cvtpk2(st[2 * ks + 1][2], st[2 * ks + 1][3]);
    plane32_swap(a0, b0);
    plane16_swap(a0, b0);
    plane32_swap(a1, b1);
    plane16_swap(a1, b1);
    union { unsigned u[4]; s16x8 v; } pu;
    pu.u[0] = a0; pu.u[1] = a1; pu.u[2] = b0; pu.u[3] = b1;
    pb[ks] = pu.v;
  }

  // O^T += V * P
  __builtin_amdgcn_s_setprio(1);
#pragma unroll
  for (int ks = 0; ks < 2; ++ks)
#pragma unroll
    for (int dsub = 0; dsub < 4; ++dsub) {
      s16x8 a = *(const s16x8*)&Vsb[(dsub * 2 + ks) * 520 + lane * 8];
      ot[dsub] = __builtin_amdgcn_mfma_f32_16x16x32_bf16(a, pb[ks], ot[dsub], 0, 0, 0);
    }
  __builtin_amdgcn_s_setprio(0);
}

__global__ __launch_bounds__(256, 8) void attn_kernel5(
    const u16* __restrict__ Qt, const u16* __restrict__ Kt,
    const u16* __restrict__ Vb, u16* __restrict__ P0, u16* __restrict__ P1,
    float* __restrict__ mlbuf)
{
  const int b = blockIdx.z, h = blockIdx.y;
  const int xb = blockIdx.x;
  const int half = xb >> 6, iblk = xb & 63;
  const int tid = threadIdx.x;
  const int wave = tid >> 6, lane = tid & 63;
  const int n16 = lane & 15, quad = lane >> 4;
  const int i0w = iblk * 64 + wave * 16;

  __shared__ u16 Ks[8 * 520];
  __shared__ u16 Vs[8 * 520];

  const u16* Qb = Qt + (size_t)b * NPIX * 256;
  const u16* Kb = Kt + (size_t)b * NPIX * 256;
  const u16* Vg = Vb + ((size_t)b * CCH + h * 64) * NPIX;

  // Q fragments (B-op: lane holds i=n16, 8 consecutive d)
  s16x8 qf[2];
#pragma unroll
  for (int ks = 0; ks < 2; ++ks)
    qf[ks] = *(const s16x8*)&Qb[(size_t)(i0w + n16) * 256 + h * 64 + ks * 32 + quad * 8];

  f32x4 ot[4];
#pragma unroll
  for (int a = 0; a < 4; ++a) ot[a] = (f32x4){0.f, 0.f, 0.f, 0.f};
  float m_i = -1e30f;
  float l_i = 0.f;

  // staging indices: 256 threads cover 64 rows x 4 x 16ch chunks
  const int sj = tid >> 2;          // row (j for K, d for V)
  const int part = tid & 3;         // which 16-channel chunk
  const int sh = part >> 1;
  const int rr0 = (part & 1) * 2;
  const int sbase = ((sj >> 4) * 2 + sh) * 520 + (sj & 15) * 8;
  const int jbase = half * 2048;

  s16x8 k0, k1, v0, v1;

#pragma unroll 1
  for (int t = 0; t < 32; ++t) {
    kv_load(Kb, Vg, h, jbase + t * 64, sj, part, k0, k1, v0, v1);
    __syncthreads();   // previous tile's fragment reads complete
    kv_store(Ks, Vs, sbase, rr0, k0, k1, v0, v1);
    __syncthreads();
    attn_tile(Ks, Vs, qf, lane, ot, m_i, l_i);
  }

  // epilogue: normalize, store partial O^T rows (bf16) + (m,l)
  float rl = 1.0f / l_i;
  u16* dst = (half == 0) ? P0 : P1;
#pragma unroll
  for (int dsub = 0; dsub < 4; ++dsub) {
    uint2 w2;
    w2.x = cvtpk2(ot[dsub][0] * rl, ot[dsub][1] * rl);
    w2.y = cvtpk2(ot[dsub][2] * rl, ot[dsub][3] * rl);
    size_t addr = (size_t)((size_t)b * NPIX + i0w + n16) * 256 + h * 64 + dsub * 16 + quad * 4;
    *(uint2*)&dst[addr] = w2;
  }
  if (quad == 0) {
    int idx = half * 65536 + b * 16384 + h * 4096 + i0w + n16;
    float2 ml; ml.x = m_i; ml.y = l_i;
    *(float2*)&mlbuf[idx * 2] = ml;
  }
}

// ---------------- Combine split-KV halves: Ot = (c0*O0 + c1*O1)/(c0+c1) ----------------
// P1 region IS Ot; in-place rewrite (each thread reads its bytes before writing).
__global__ __launch_bounds__(256) void combine_kernel(
    const u16* __restrict__ P0, u16* __restrict__ Ot, const float* __restrict__ mlbuf)
{
  const int t = threadIdx.x;
  const int r = blockIdx.x * 32 + (t >> 3);      // (b,i) flat row 0..16383
  const int seg = t & 7;                          // 32-ch segment
  const int b = r >> 12, i = r & 4095;
  const int h = seg >> 1;
  const int idx = b * 16384 + h * 4096 + i;
  float2 ml0 = *(const float2*)&mlbuf[(size_t)idx * 2];
  float2 ml1 = *(const float2*)&mlbuf[(size_t)(65536 + idx) * 2];
  float m = fmaxf(ml0.x, ml1.x);
  float c0 = ml0.y * __builtin_amdgcn_exp2f(ml0.x - m);
  float c1 = ml1.y * __builtin_amdgcn_exp2f(ml1.x - m);
  float rn = 1.0f / (c0 + c1);
  float w0 = c0 * rn, w1 = c1 * rn;
  size_t base = (size_t)r * 256 + seg * 32;
#pragma unroll
  for (int p = 0; p < 4; ++p) {
    s16x8 a = *(const s16x8*)&P0[base + p * 8];
    s16x8 c = *(const s16x8*)&Ot[base + p * 8];
    union { unsigned u[4]; s16x8 v; } o;
#pragma unroll
    for (int e = 0; e < 4; ++e) {
      float lo = w0 * bf16_to_f32((unsigned short)a[2 * e])     + w1 * bf16_to_f32((unsigned short)c[2 * e]);
      float hi = w0 * bf16_to_f32((unsigned short)a[2 * e + 1]) + w1 * bf16_to_f32((unsigned short)c[2 * e + 1]);
      o.u[e] = cvtpk2(lo, hi);
    }
    *(s16x8*)&Ot[base + p * 8] = o.v;
  }
}

// ---------------- Proj GEMM (bf16 MFMA) + bias + residual, fp32 out ----------------
__global__ __launch_bounds__(256) void proj_gemm_kernel(
    const u16* __restrict__ Wp, const float* __restrict__ proj_b, const u16* __restrict__ Ot,
    const float* __restrict__ x, float* __restrict__ out)
{
  const int nblk = blockIdx.x, m0 = blockIdx.y * 64;
  const int tid = threadIdx.x, wave = tid >> 6, lane = tid & 63;
  const int n16 = lane & 15, quad = lane >> 4;
  const int n0 = nblk * 128 + wave * 32;

  f32x4 acc[4][2];
#pragma unroll
  for (int a = 0; a < 4; ++a)
#pragma unroll
    for (int c = 0; c < 2; ++c) acc[a][c] = (f32x4){0.f, 0.f, 0.f, 0.f};

#pragma unroll
  for (int k0 = 0; k0 < 256; k0 += 32) {
    s16x8 af[4], bfr[2];
#pragma unroll
    for (int msub = 0; msub < 4; ++msub)
      af[msub] = *(const s16x8*)&Wp[(size_t)(m0 + msub * 16 + n16) * 256 + k0 + quad * 8];
#pragma unroll
    for (int nsub = 0; nsub < 2; ++nsub)
      bfr[nsub] = *(const s16x8*)&Ot[(size_t)(n0 + nsub * 16 + n16) * 256 + k0 + quad * 8];
#pragma unroll
    for (int msub = 0; msub < 4; ++msub)
#pragma unroll
      for (int nsub = 0; nsub < 2; ++nsub)
        acc[msub][nsub] = __builtin_amdgcn_mfma_f32_16x16x32_bf16(af[msub], bfr[nsub], acc[msub][nsub], 0, 0, 0);
  }

  __shared__ float T[64 * 132];
#pragma unroll
  for (int msub = 0; msub < 4; ++msub)
#pragma unroll
    for (int nsub = 0; nsub < 2; ++nsub) {
      int ncol = wave * 32 + nsub * 16 + n16;
#pragma unroll
      for (int r = 0; r < 4; ++r) {
        int m = msub * 16 + quad * 4 + r;
        T[m * 132 + ncol] = acc[msub][nsub][r];
      }
    }
  __syncthreads();
  const int b = (nblk * 128) >> 12, i0n = (nblk * 128) & 4095;
#pragma unroll
  for (int it = 0; it < 8; ++it) {
    int linear = it * 256 + tid;
    int m = linear >> 5, ch = linear & 31;
    f32x4 v = *(const f32x4*)&T[m * 132 + ch * 4];
    float bs = proj_b[m0 + m];
    size_t g = ((size_t)b * CCH + m0 + m) * NPIX + i0n + ch * 4;
    float4 rv = *(const float4*)&x[g];
    float4 o;
    o.x = v[0] + bs + rv.x; o.y = v[1] + bs + rv.y;
    o.z = v[2] + bs + rv.z; o.w = v[3] + bs + rv.w;
    *(float4*)&out[g] = o;
  }
}

extern "C" void kernel_launch(void* const* d_in, const int* in_sizes, int n_in,
                              void* d_out, int out_size, void* d_ws, size_t ws_size,
                              hipStream_t stream)
{
  const float* x      = (const float*)d_in[0];
  const float* gn_w   = (const float*)d_in[1];
  const float* gn_b   = (const float*)d_in[2];
  const float* qkv_w  = (const float*)d_in[3];
  const float* qkv_b  = (const float*)d_in[4];
  const float* proj_w = (const float*)d_in[5];
  const float* proj_b = (const float*)d_in[6];
  float* out = (float*)d_out;

  float* ws    = (float*)d_ws;
  float* alpha = ws;                       // 1024
  float* beta  = ws + 1024;                // 1024
  float* biasq = ws + 2048;                // 768
  double2* partials = (double2*)(ws + 2816); // 256 double2 -> ends 3840
  u16*   wq    = (u16*)(ws + 4096);        // 196608 shorts
  u16*   wp    = (u16*)(ws + 102400);      // 65536 shorts
  u16*   Xt    = (u16*)(ws + 135168);      // 4*4096*256 shorts = 2097152 floats
  u16*   Qt    = (u16*)(ws + 2232320);
  u16*   Kt    = (u16*)(ws + 4329472);
  u16*   Vb    = (u16*)(ws + 6426624);
  u16*   Ot    = (u16*)(ws + 8523776);     // ends 10620928
  float* mlbuf = ws + 10620928;            // 2*65536*2 floats -> ends 10883072 (~43.5 MB)

  // P0 (half-0 partial O) overlays Xt (dead after qkv_gemm); P1 = Ot (combined in place).
  u16* P0 = Xt;

  gn_stats_part<<<256, 256, 0, stream>>>(x, partials);
  wcvt_kernel<<<1024, 256, 0, stream>>>(qkv_w, proj_w, qkv_b, partials, gn_w, gn_b,
                                        wq, wp, biasq, alpha, beta);
  gn_apply_t_kernel<<<dim3(64, 4, 4), 256, 0, stream>>>(x, alpha, beta, Xt);
  qkv_gemm_kernel<<<dim3(128, 12), 256, 0, stream>>>(wq, biasq, Xt, Qt, Kt, Vb);
  attn_kernel5<<<dim3(128, 4, 4), 256, 0, stream>>>(Qt, Kt, Vb, P0, Ot, mlbuf);
  combine_kernel<<<512, 256, 0, stream>>>(P0, Ot, mlbuf);
  proj_gemm_kernel<<<dim3(128, 4), 256, 0, stream>>>(wp, proj_b, Ot, x, out);
}

// Round 9
// 237.035 us; speedup vs baseline: 1.0865x; 1.0865x over previous
//
#include <hip/hip_runtime.h>
#include <math.h>

#define NPIX 4096
#define CCH 256

typedef __attribute__((ext_vector_type(4))) float f32x4;
typedef __attribute__((ext_vector_type(16))) float f32x16;
typedef __attribute__((ext_vector_type(8))) short s16x8;
typedef unsigned short u16;

__device__ __forceinline__ short bf16_rne(float x) {
  union { float f; unsigned u; } c; c.f = x;
  unsigned r = c.u + 0x7FFF + ((c.u >> 16) & 1);
  return (short)(r >> 16);
}
__device__ __forceinline__ unsigned cvtpk2(float lo, float hi) {
  unsigned r;
  asm("v_cvt_pk_bf16_f32 %0, %1, %2" : "=v"(r) : "v"(lo), "v"(hi));
  return r;
}
__device__ __forceinline__ unsigned pack2(float a, float b) {
  return cvtpk2(a, b);
}
__device__ __forceinline__ float max3f(float a, float b, float c) {
  float d;
  asm("v_max3_f32 %0, %1, %2, %3" : "=v"(d) : "v"(a), "v"(b), "v"(c));
  return d;
}
__device__ __forceinline__ float bf16_to_f32(unsigned short v) {
  return __uint_as_float(((unsigned)v) << 16);
}

// permlane32_swap via builtin (compiler-managed hazards — R2 lesson).
// TRUE semantics (R7 lesson): swap(a,b) -> a' = [a.lo, b.lo], b' = [a.hi, b.hi]
// (b' lanes 0-31 receive a's upper half; a' lanes 32-63 receive b's lower half.)
__device__ __forceinline__ void plane32_swap(unsigned& a, unsigned& b) {
#if __has_builtin(__builtin_amdgcn_permlane32_swap)
  auto r = __builtin_amdgcn_permlane32_swap(a, b, false, false);
  a = r[0]; b = r[1];
#else
  asm("s_nop 2\n\tv_permlane32_swap_b32 %0, %1\n\ts_nop 2" : "+v"(a), "+v"(b));
#endif
}
// cross-half (lane l <-> l+32) reductions, VALU pipe only
__device__ __forceinline__ float red_max_half(float x) {
  unsigned a = __float_as_uint(x), b = a;
  plane32_swap(a, b);
  return fmaxf(__uint_as_float(a), __uint_as_float(b));
}
__device__ __forceinline__ float red_sum_half(float x) {
  unsigned a = __float_as_uint(x), b = a;
  plane32_swap(a, b);
  return __uint_as_float(a) + __uint_as_float(b);
}

#define QSCALE 0.18033688011f   /* 0.125 * log2(e) */

// ---------------- GroupNorm partial stats: 256 blocks = (b, g, chunk) ----------------
__global__ __launch_bounds__(256) void gn_stats_part(
    const float* __restrict__ x, double2* __restrict__ partials)
{
  const int blk = blockIdx.x;
  const int bg = blk >> 3, chunk = blk & 7;
  const float4* base = (const float4*)(x + (size_t)bg * 131072 + (size_t)chunk * 16384);
  double s = 0.0, ss = 0.0;
  for (int idx = threadIdx.x; idx < 4096; idx += 256) {
    float4 v = base[idx];
    s  += (double)v.x + (double)v.y + (double)v.z + (double)v.w;
    ss += (double)v.x * v.x + (double)v.y * v.y + (double)v.z * v.z + (double)v.w * v.w;
  }
  __shared__ double rs[256], rss[256];
  rs[threadIdx.x] = s; rss[threadIdx.x] = ss;
  __syncthreads();
  for (int off = 128; off > 0; off >>= 1) {
    if (threadIdx.x < off) { rs[threadIdx.x] += rs[threadIdx.x + off]; rss[threadIdx.x] += rss[threadIdx.x + off]; }
    __syncthreads();
  }
  if (threadIdx.x == 0) {
    double2 p; p.x = rs[0]; p.y = rss[0];
    partials[blk] = p;
  }
}

// ---------------- Weight/bias convert + GN stats finalize ----------------
__global__ __launch_bounds__(256) void wcvt_kernel(
    const float* __restrict__ qkv_w, const float* __restrict__ proj_w, const float* __restrict__ qkv_b,
    const double2* __restrict__ partials, const float* __restrict__ gn_w, const float* __restrict__ gn_b,
    u16* __restrict__ wq, u16* __restrict__ wp, float* __restrict__ biasq,
    float* __restrict__ alpha, float* __restrict__ beta)
{
  int idx = blockIdx.x * 256 + threadIdx.x;   // 0..262143
  if (idx < 196608) {
    float v = qkv_w[idx];
    if (idx < 65536) v *= QSCALE;             // q rows (o < 256)
    wq[idx] = (u16)bf16_rne(v);
  } else {
    int j = idx - 196608;
    wp[j] = (u16)bf16_rne(proj_w[j]);
  }
  if (idx < 768) {
    float bv = qkv_b[idx];
    if (idx < 256) bv *= QSCALE;
    biasq[idx] = bv;
  }
  if (blockIdx.x == 0) {
    __shared__ float sm[32], sr[32];
    const int tid = threadIdx.x;
    if (tid < 32) {
      double s = 0.0, ss = 0.0;
      for (int c = 0; c < 8; ++c) { double2 p = partials[tid * 8 + c]; s += p.x; ss += p.y; }
      double mean = s / 131072.0;
      double var  = ss / 131072.0 - mean * mean;
      sm[tid] = (float)mean;
      sr[tid] = (float)(1.0 / sqrt(var + 1e-5));
    }
    __syncthreads();
#pragma unroll
    for (int p = 0; p < 4; ++p) {
      int e = p * 256 + tid;            // 0..1023 = b*256 + ch
      int ch = e & 255;
      int bg = (e >> 8) * 8 + (ch >> 5);
      float a = sr[bg] * gn_w[ch];
      alpha[e] = a;
      beta[e]  = gn_b[ch] - sm[bg] * a;
    }
  }
}

// ---------------- GN apply + transpose: x[b][c][n] fp32 -> Xt[b][n][c] bf16 ----------------
__global__ __launch_bounds__(256) void gn_apply_t_kernel(
    const float* __restrict__ x, const float* __restrict__ alpha, const float* __restrict__ beta,
    u16* __restrict__ Xt)
{
  const int b = blockIdx.z, c0 = blockIdx.y * 64, n0 = blockIdx.x * 64;
  const int tid = threadIdx.x;
  __shared__ u16 T[64 * 68];
  const int n4 = (tid & 15) * 4, cr = tid >> 4;
#pragma unroll
  for (int p = 0; p < 4; ++p) {
    int cl = cr + 16 * p;
    int c = c0 + cl;
    float a = alpha[b * CCH + c], bt = beta[b * CCH + c];
    float4 v = *(const float4*)&x[((size_t)b * CCH + c) * NPIX + n0 + n4];
    T[(n4 + 0) * 68 + cl] = (u16)bf16_rne(v.x * a + bt);
    T[(n4 + 1) * 68 + cl] = (u16)bf16_rne(v.y * a + bt);
    T[(n4 + 2) * 68 + cl] = (u16)bf16_rne(v.z * a + bt);
    T[(n4 + 3) * 68 + cl] = (u16)bf16_rne(v.w * a + bt);
  }
  __syncthreads();
#pragma unroll
  for (int it = 0; it < 2; ++it) {
    int linear = it * 256 + tid;
    int n = linear >> 3, ch = linear & 7;
    s16x8 v = *(const s16x8*)&T[n * 68 + ch * 8];
    *(s16x8*)&Xt[((size_t)b * NPIX + n0 + n) * CCH + c0 + ch * 8] = v;
  }
}

// ---------------- QKV GEMM (bf16 MFMA): D[m][n] = W[m][k] Xt[n][k] + bias ----------------
__global__ __launch_bounds__(256) void qkv_gemm_kernel(
    const u16* __restrict__ Wbf, const float* __restrict__ biasv, const u16* __restrict__ Xt,
    u16* __restrict__ Qt, u16* __restrict__ Kt, u16* __restrict__ Vb)
{
  const int nblk = blockIdx.x, m0 = blockIdx.y * 64;
  const int tid = threadIdx.x, wave = tid >> 6, lane = tid & 63;
  const int n16 = lane & 15, quad = lane >> 4;
  const int n0 = nblk * 128 + wave * 32;   // flat row (b*4096 + i)

  f32x4 acc[4][2];
#pragma unroll
  for (int a = 0; a < 4; ++a)
#pragma unroll
    for (int c = 0; c < 2; ++c) acc[a][c] = (f32x4){0.f, 0.f, 0.f, 0.f};

#pragma unroll
  for (int k0 = 0; k0 < 256; k0 += 32) {
    s16x8 af[4], bfr[2];
#pragma unroll
    for (int msub = 0; msub < 4; ++msub)
      af[msub] = *(const s16x8*)&Wbf[(size_t)(m0 + msub * 16 + n16) * 256 + k0 + quad * 8];
#pragma unroll
    for (int nsub = 0; nsub < 2; ++nsub)
      bfr[nsub] = *(const s16x8*)&Xt[(size_t)(n0 + nsub * 16 + n16) * 256 + k0 + quad * 8];
#pragma unroll
    for (int msub = 0; msub < 4; ++msub)
#pragma unroll
      for (int nsub = 0; nsub < 2; ++nsub)
        acc[msub][nsub] = __builtin_amdgcn_mfma_f32_16x16x32_bf16(af[msub], bfr[nsub], acc[msub][nsub], 0, 0, 0);
  }

  __shared__ u16 T[8704];   // qk: [n128][m 68]; v: [m64][n 136]
  if (m0 < 512) {
    // bias + pack, store transposed tile [n][m]
#pragma unroll
    for (int msub = 0; msub < 4; ++msub)
#pragma unroll
      for (int nsub = 0; nsub < 2; ++nsub) {
        float b0 = biasv[m0 + msub * 16 + quad * 4 + 0];
        float b1 = biasv[m0 + msub * 16 + quad * 4 + 1];
        float b2 = biasv[m0 + msub * 16 + quad * 4 + 2];
        float b3 = biasv[m0 + msub * 16 + quad * 4 + 3];
        uint2 w2;
        w2.x = pack2(acc[msub][nsub][0] + b0, acc[msub][nsub][1] + b1);
        w2.y = pack2(acc[msub][nsub][2] + b2, acc[msub][nsub][3] + b3);
        *(uint2*)&T[(wave * 32 + nsub * 16 + n16) * 68 + msub * 16 + quad * 4] = w2;
      }
    __syncthreads();
    u16* dst = (m0 < 256) ? Qt : Kt;
    const int coff = m0 & 255;
#pragma unroll
    for (int it = 0; it < 4; ++it) {
      int linear = it * 256 + tid;
      int n = linear >> 3, ch = linear & 7;
      s16x8 v = *(const s16x8*)&T[n * 68 + ch * 8];
      *(s16x8*)&dst[(size_t)(nblk * 128 + n) * 256 + coff + ch * 8] = v;
    }
  } else {
    // V: store [m][n] natural rows
#pragma unroll
    for (int msub = 0; msub < 4; ++msub)
#pragma unroll
      for (int nsub = 0; nsub < 2; ++nsub) {
        int ncol = wave * 32 + nsub * 16 + n16;
#pragma unroll
        for (int r = 0; r < 4; ++r) {
          int m = msub * 16 + quad * 4 + r;
          T[m * 136 + ncol] = (u16)bf16_rne(acc[msub][nsub][r] + biasv[m0 + m]);
        }
      }
    __syncthreads();
    const int b = (nblk * 128) >> 12, i0n = (nblk * 128) & 4095;
#pragma unroll
    for (int it = 0; it < 4; ++it) {
      int linear = it * 256 + tid;
      int mloc = linear >> 4, ch = linear & 15;
      s16x8 v = *(const s16x8*)&T[mloc * 136 + ch * 8];
      int c = (m0 - 512) + mloc;
      *(s16x8*)&Vb[((size_t)b * CCH + c) * NPIX + i0n + ch * 8] = v;
    }
  }
}

// ---------------- MFMA flash attention v6b: 32x32x16 MFMA, split-KV x2 ----------------
// LDS-bandwidth fix: 32x32x16 gives 2x FLOP per LDS byte vs 16x16x32.
// 4 waves x 32 i-rows = 128 rows/block; grid (64,4,4): x>>5 = KV half.
// LDS frag layout: frag f = sub*4 + q (8 frags of 1KB), lane slot l*16B.
//   K frag (jsub,kq): lane l -> K[j = jsub*32 + (l&31)][k = kq*16 + (l>>5)*8 + 0..7]
//   V frag (dsub,jq): lane l -> V[d = dsub*32 + (l&31)][jl = jq*16 + (l>>5)*8 + 0..7]
__device__ __forceinline__ void kv_load6(
    const u16* __restrict__ Kb, const u16* __restrict__ Vg, int h, int j0, int sj, int part,
    s16x8& k0, s16x8& k1, s16x8& v0, s16x8& v1)
{
  const s16x8* kp = (const s16x8*)&Kb[(size_t)(j0 + sj) * 256 + h * 64 + part * 16];
  const s16x8* vp = (const s16x8*)&Vg[(size_t)sj * NPIX + j0 + part * 16];
  k0 = kp[0]; k1 = kp[1]; v0 = vp[0]; v1 = vp[1];
}
__device__ __forceinline__ void kv_store6(
    u16* Ksb, u16* Vsb, int sbase,
    s16x8 k0, s16x8 k1, s16x8 v0, s16x8 v1)
{
  *(s16x8*)&Ksb[sbase]       = k0;   // k/j_local low 8 -> lane half 0
  *(s16x8*)&Ksb[sbase + 256] = k1;   // high 8 -> lane half 1 (+32 lanes * 8 u16)
  *(s16x8*)&Vsb[sbase]       = v0;
  *(s16x8*)&Vsb[sbase + 256] = v1;
}

__device__ __forceinline__ void attn_tile6(
    const u16* Ksb, const u16* Vsb, const s16x8 qf[4], int lane,
    f32x16 ot[2], float& m_i, float& l_i)
{
  f32x16 st[2];
#pragma unroll
  for (int r = 0; r < 16; ++r) { st[0][r] = 0.f; st[1][r] = 0.f; }

  // S^T[j][i] = K[j][k] Q[i][k]: A = K frag (m=j), B = Q frag (n=i)
  __builtin_amdgcn_s_setprio(1);
#pragma unroll
  for (int kq = 0; kq < 4; ++kq)
#pragma unroll
    for (int jsub = 0; jsub < 2; ++jsub) {
      s16x8 a = *(const s16x8*)&Ksb[(jsub * 4 + kq) * 512 + lane * 8];
      st[jsub] = __builtin_amdgcn_mfma_f32_32x32x16_bf16(a, qf[kq], st[jsub], 0, 0, 0);
    }
  __builtin_amdgcn_s_setprio(0);

  // row max over 32 local values (max3 tree) + 1 cross-half swap
  float c0 = max3f(st[0][0],  st[0][1],  st[0][2]);
  float c1 = max3f(st[0][3],  st[0][4],  st[0][5]);
  float c2 = max3f(st[0][6],  st[0][7],  st[0][8]);
  float c3 = max3f(st[0][9],  st[0][10], st[0][11]);
  float c4 = max3f(st[0][12], st[0][13], st[0][14]);
  float c5 = max3f(st[0][15], st[1][0],  st[1][1]);
  float c6 = max3f(st[1][2],  st[1][3],  st[1][4]);
  float c7 = max3f(st[1][5],  st[1][6],  st[1][7]);
  float c8 = max3f(st[1][8],  st[1][9],  st[1][10]);
  float c9 = max3f(st[1][11], st[1][12], st[1][13]);
  float d0 = max3f(c0, c1, c2);
  float d1 = max3f(c3, c4, c5);
  float d2 = max3f(c6, c7, c8);
  float d3 = max3f(c9, st[1][14], st[1][15]);
  float tm = fmaxf(fmaxf(d0, d1), fmaxf(d2, d3));
  tm = red_max_half(tm);

  // defer-max: only rescale when max grew by >8 (log2 domain)
  if (__any(tm > m_i + 8.0f)) {
    float mn = fmaxf(m_i, tm);
    float al = __builtin_amdgcn_exp2f(m_i - mn);
    m_i = mn;
    l_i *= al;
#pragma unroll
    for (int r = 0; r < 16; ++r) { ot[0][r] *= al; ot[1][r] *= al; }
  }

#pragma unroll
  for (int f = 0; f < 2; ++f)
#pragma unroll
    for (int r = 0; r < 16; ++r)
      st[f][r] = __builtin_amdgcn_exp2f(st[f][r] - m_i);

  float s0 = (st[0][0] + st[0][1]) + (st[0][2]  + st[0][3]);
  float s1 = (st[0][4] + st[0][5]) + (st[0][6]  + st[0][7]);
  float s2 = (st[0][8] + st[0][9]) + (st[0][10] + st[0][11]);
  float s3 = (st[0][12]+ st[0][13])+ (st[0][14] + st[0][15]);
  float s4 = (st[1][0] + st[1][1]) + (st[1][2]  + st[1][3]);
  float s5 = (st[1][4] + st[1][5]) + (st[1][6]  + st[1][7]);
  float s6 = (st[1][8] + st[1][9]) + (st[1][10] + st[1][11]);
  float s7 = (st[1][12]+ st[1][13])+ (st[1][14] + st[1][15]);
  float ps = ((s0 + s1) + (s2 + s3)) + ((s4 + s5) + (s6 + s7));
  ps = red_sum_half(ps);
  l_i += ps;

  // P^T -> PV B-frags per j-16-block jq, then O^T += V * P.
  // Target lane (half hi') B word w holds j_loc16 = hi'*8 + e, e = 2w,2w+1.
  // Source reg r = 4*(2*(jq&1) + hi') + (e&3), source HALF = e>>2.
  // u0,u1 = regs targeting hi'=0 (rbase b0); u2,u3 = regs targeting hi'=1 (b1).
  //   word0 needs [u0@h0 | u2@h0] = [u0.lo, u2.lo];  word2 = [u0.hi, u2.hi]
  //   word1 needs [u1.lo, u3.lo];                    word3 = [u1.hi, u3.hi]
  // With swap(a,b) -> a'=[a.lo,b.lo], b'=[a.hi,b.hi]:
  //   swap(u0,u2): u0'=word0, u2'=word2;  swap(u1,u3): u1'=word1, u3'=word3.
  // (R7 bug: arguments were inverted -> every B-frag scrambled.)
#pragma unroll
  for (int jq = 0; jq < 4; ++jq) {
    const int jsub = jq >> 1;
    const int b0 = (jq & 1) * 8;
    const int b1 = b0 + 4;
    unsigned u0 = cvtpk2(st[jsub][b0 + 0], st[jsub][b0 + 1]);
    unsigned u1 = cvtpk2(st[jsub][b0 + 2], st[jsub][b0 + 3]);
    unsigned u2 = cvtpk2(st[jsub][b1 + 0], st[jsub][b1 + 1]);
    unsigned u3 = cvtpk2(st[jsub][b1 + 2], st[jsub][b1 + 3]);
    plane32_swap(u0, u2);
    plane32_swap(u1, u3);
    union { unsigned u[4]; s16x8 v; } pu;
    pu.u[0] = u0; pu.u[1] = u1; pu.u[2] = u2; pu.u[3] = u3;
    __builtin_amdgcn_s_setprio(1);
#pragma unroll
    for (int dsub = 0; dsub < 2; ++dsub) {
      s16x8 a = *(const s16x8*)&Vsb[(dsub * 4 + jq) * 512 + lane * 8];
      ot[dsub] = __builtin_amdgcn_mfma_f32_32x32x16_bf16(a, pu.v, ot[dsub], 0, 0, 0);
    }
    __builtin_amdgcn_s_setprio(0);
  }
}

__global__ __launch_bounds__(256, 4) void attn_kernel6(
    const u16* __restrict__ Qt, const u16* __restrict__ Kt,
    const u16* __restrict__ Vb, u16* __restrict__ P0, u16* __restrict__ P1,
    float* __restrict__ mlbuf)
{
  const int b = blockIdx.z, h = blockIdx.y;
  const int xb = blockIdx.x;
  const int half = xb >> 5, iblk = xb & 31;
  const int tid = threadIdx.x;
  const int wave = tid >> 6, lane = tid & 63;
  const int i0w = iblk * 128 + wave * 32;

  __shared__ u16 Ks[2][4096];
  __shared__ u16 Vs[2][4096];

  const u16* Qb = Qt + (size_t)b * NPIX * 256;
  const u16* Kb = Kt + (size_t)b * NPIX * 256;
  const u16* Vg = Vb + ((size_t)b * CCH + h * 64) * NPIX;

  // Q B-frags (n=i=lane&31, k = kq*16 + (lane>>5)*8 + 0..7)
  s16x8 qf[4];
#pragma unroll
  for (int kq = 0; kq < 4; ++kq)
    qf[kq] = *(const s16x8*)&Qb[(size_t)(i0w + (lane & 31)) * 256 + h * 64 + kq * 16 + (lane >> 5) * 8];

  f32x16 ot[2];
#pragma unroll
  for (int r = 0; r < 16; ++r) { ot[0][r] = 0.f; ot[1][r] = 0.f; }
  float m_i = -1e30f;
  float l_i = 0.f;

  // staging: 256 threads = 64 rows x 4 k/j-16-chunks (32B each)
  const int sj = tid >> 2;
  const int part = tid & 3;
  const int sbase = ((sj >> 5) * 4 + part) * 512 + (sj & 31) * 8;
  const int jbase = half * 2048;

  s16x8 k0, k1, v0, v1;

  kv_load6(Kb, Vg, h, jbase, sj, part, k0, k1, v0, v1);
  kv_store6(Ks[0], Vs[0], sbase, k0, k1, v0, v1);
  __syncthreads();

#pragma unroll 1
  for (int t = 0; t < 30; t += 2) {
    kv_load6(Kb, Vg, h, jbase + (t + 1) * 64, sj, part, k0, k1, v0, v1);
    attn_tile6(Ks[0], Vs[0], qf, lane, ot, m_i, l_i);
    kv_store6(Ks[1], Vs[1], sbase, k0, k1, v0, v1);
    __syncthreads();
    kv_load6(Kb, Vg, h, jbase + (t + 2) * 64, sj, part, k0, k1, v0, v1);
    attn_tile6(Ks[1], Vs[1], qf, lane, ot, m_i, l_i);
    kv_store6(Ks[0], Vs[0], sbase, k0, k1, v0, v1);
    __syncthreads();
  }
  kv_load6(Kb, Vg, h, jbase + 31 * 64, sj, part, k0, k1, v0, v1);
  attn_tile6(Ks[0], Vs[0], qf, lane, ot, m_i, l_i);
  kv_store6(Ks[1], Vs[1], sbase, k0, k1, v0, v1);
  __syncthreads();
  attn_tile6(Ks[1], Vs[1], qf, lane, ot, m_i, l_i);

  // epilogue: normalize, store partial O^T (bf16) + (m,l)
  // O^T layout: col = i = lane&31; row d = dsub*32 + 8*q + 4*(lane>>5) + (r&3)
  float rl = 1.0f / l_i;
  u16* dst = (half == 0) ? P0 : P1;
  const size_t rowbase = (size_t)((size_t)b * NPIX + i0w + (lane & 31)) * 256 + h * 64 + (lane >> 5) * 4;
#pragma unroll
  for (int dsub = 0; dsub < 2; ++dsub)
#pragma unroll
    for (int q = 0; q < 4; ++q) {
      uint2 w2;
      w2.x = cvtpk2(ot[dsub][4 * q + 0] * rl, ot[dsub][4 * q + 1] * rl);
      w2.y = cvtpk2(ot[dsub][4 * q + 2] * rl, ot[dsub][4 * q + 3] * rl);
      *(uint2*)&dst[rowbase + dsub * 32 + q * 8] = w2;
    }
  if (lane < 32) {
    int idx = half * 65536 + b * 16384 + h * 4096 + i0w + lane;
    float2 ml; ml.x = m_i; ml.y = l_i;
    *(float2*)&mlbuf[idx * 2] = ml;
  }
}

// ---------------- Combine split-KV halves: Ot = (c0*O0 + c1*O1)/(c0+c1) ----------------
// P1 region IS Ot; in-place rewrite (each thread reads its bytes before writing).
__global__ __launch_bounds__(256) void combine_kernel(
    const u16* __restrict__ P0, u16* __restrict__ Ot, const float* __restrict__ mlbuf)
{
  const int t = threadIdx.x;
  const int r = blockIdx.x * 32 + (t >> 3);      // (b,i) flat row 0..16383
  const int seg = t & 7;                          // 32-ch segment
  const int b = r >> 12, i = r & 4095;
  const int h = seg >> 1;
  const int idx = b * 16384 + h * 4096 + i;
  float2 ml0 = *(const float2*)&mlbuf[(size_t)idx * 2];
  float2 ml1 = *(const float2*)&mlbuf[(size_t)(65536 + idx) * 2];
  float m = fmaxf(ml0.x, ml1.x);
  float c0 = ml0.y * __builtin_amdgcn_exp2f(ml0.x - m);
  float c1 = ml1.y * __builtin_amdgcn_exp2f(ml1.x - m);
  float rn = 1.0f / (c0 + c1);
  float w0 = c0 * rn, w1 = c1 * rn;
  size_t base = (size_t)r * 256 + seg * 32;
#pragma unroll
  for (int p = 0; p < 4; ++p) {
    s16x8 a = *(const s16x8*)&P0[base + p * 8];
    s16x8 c = *(const s16x8*)&Ot[base + p * 8];
    union { unsigned u[4]; s16x8 v; } o;
#pragma unroll
    for (int e = 0; e < 4; ++e) {
      float lo = w0 * bf16_to_f32((unsigned short)a[2 * e])     + w1 * bf16_to_f32((unsigned short)c[2 * e]);
      float hi = w0 * bf16_to_f32((unsigned short)a[2 * e + 1]) + w1 * bf16_to_f32((unsigned short)c[2 * e + 1]);
      o.u[e] = cvtpk2(lo, hi);
    }
    *(s16x8*)&Ot[base + p * 8] = o.v;
  }
}

// ---------------- Proj GEMM (bf16 MFMA) + bias + residual, fp32 out ----------------
__global__ __launch_bounds__(256) void proj_gemm_kernel(
    const u16* __restrict__ Wp, const float* __restrict__ proj_b, const u16* __restrict__ Ot,
    const float* __restrict__ x, float* __restrict__ out)
{
  const int nblk = blockIdx.x, m0 = blockIdx.y * 64;
  const int tid = threadIdx.x, wave = tid >> 6, lane = tid & 63;
  const int n16 = lane & 15, quad = lane >> 4;
  const int n0 = nblk * 128 + wave * 32;

  f32x4 acc[4][2];
#pragma unroll
  for (int a = 0; a < 4; ++a)
#pragma unroll
    for (int c = 0; c < 2; ++c) acc[a][c] = (f32x4){0.f, 0.f, 0.f, 0.f};

#pragma unroll
  for (int k0 = 0; k0 < 256; k0 += 32) {
    s16x8 af[4], bfr[2];
#pragma unroll
    for (int msub = 0; msub < 4; ++msub)
      af[msub] = *(const s16x8*)&Wp[(size_t)(m0 + msub * 16 + n16) * 256 + k0 + quad * 8];
#pragma unroll
    for (int nsub = 0; nsub < 2; ++nsub)
      bfr[nsub] = *(const s16x8*)&Ot[(size_t)(n0 + nsub * 16 + n16) * 256 + k0 + quad * 8];
#pragma unroll
    for (int msub = 0; msub < 4; ++msub)
#pragma unroll
      for (int nsub = 0; nsub < 2; ++nsub)
        acc[msub][nsub] = __builtin_amdgcn_mfma_f32_16x16x32_bf16(af[msub], bfr[nsub], acc[msub][nsub], 0, 0, 0);
  }

  __shared__ float T[64 * 132];
#pragma unroll
  for (int msub = 0; msub < 4; ++msub)
#pragma unroll
    for (int nsub = 0; nsub < 2; ++nsub) {
      int ncol = wave * 32 + nsub * 16 + n16;
#pragma unroll
      for (int r = 0; r < 4; ++r) {
        int m = msub * 16 + quad * 4 + r;
        T[m * 132 + ncol] = acc[msub][nsub][r];
      }
    }
  __syncthreads();
  const int b = (nblk * 128) >> 12, i0n = (nblk * 128) & 4095;
#pragma unroll
  for (int it = 0; it < 8; ++it) {
    int linear = it * 256 + tid;
    int m = linear >> 5, ch = linear & 31;
    f32x4 v = *(const f32x4*)&T[m * 132 + ch * 4];
    float bs = proj_b[m0 + m];
    size_t g = ((size_t)b * CCH + m0 + m) * NPIX + i0n + ch * 4;
    float4 rv = *(const float4*)&x[g];
    float4 o;
    o.x = v[0] + bs + rv.x; o.y = v[1] + bs + rv.y;
    o.z = v[2] + bs + rv.z; o.w = v[3] + bs + rv.w;
    *(float4*)&out[g] = o;
  }
}

extern "C" void kernel_launch(void* const* d_in, const int* in_sizes, int n_in,
                              void* d_out, int out_size, void* d_ws, size_t ws_size,
                              hipStream_t stream)
{
  const float* x      = (const float*)d_in[0];
  const float* gn_w   = (const float*)d_in[1];
  const float* gn_b   = (const float*)d_in[2];
  const float* qkv_w  = (const float*)d_in[3];
  const float* qkv_b  = (const float*)d_in[4];
  const float* proj_w = (const float*)d_in[5];
  const float* proj_b = (const float*)d_in[6];
  float* out = (float*)d_out;

  float* ws    = (float*)d_ws;
  float* alpha = ws;                       // 1024
  float* beta  = ws + 1024;                // 1024
  float* biasq = ws + 2048;                // 768
  double2* partials = (double2*)(ws + 2816); // 256 double2 -> ends 3840
  u16*   wq    = (u16*)(ws + 4096);        // 196608 shorts
  u16*   wp    = (u16*)(ws + 102400);      // 65536 shorts
  u16*   Xt    = (u16*)(ws + 135168);      // 4*4096*256 shorts = 2097152 floats
  u16*   Qt    = (u16*)(ws + 2232320);
  u16*   Kt    = (u16*)(ws + 4329472);
  u16*   Vb    = (u16*)(ws + 6426624);
  u16*   Ot    = (u16*)(ws + 8523776);     // ends 10620928
  float* mlbuf = ws + 10620928;            // 2*65536*2 floats -> ends 10883072 (~43.5 MB)

  // P0 (half-0 partial O) overlays Xt (dead after qkv_gemm); P1 = Ot (combined in place).
  u16* P0 = Xt;

  gn_stats_part<<<256, 256, 0, stream>>>(x, partials);
  wcvt_kernel<<<1024, 256, 0, stream>>>(qkv_w, proj_w, qkv_b, partials, gn_w, gn_b,
                                        wq, wp, biasq, alpha, beta);
  gn_apply_t_kernel<<<dim3(64, 4, 4), 256, 0, stream>>>(x, alpha, beta, Xt);
  qkv_gemm_kernel<<<dim3(128, 12), 256, 0, stream>>>(wq, biasq, Xt, Qt, Kt, Vb);
  attn_kernel6<<<dim3(64, 4, 4), 256, 0, stream>>>(Qt, Kt, Vb, P0, Ot, mlbuf);
  combine_kernel<<<512, 256, 0, stream>>>(P0, Ot, mlbuf);
  proj_gemm_kernel<<<dim3(128, 4), 256, 0, stream>>>(wp, proj_b, Ot, x, out);
}